// Round 2
// baseline (733.069 us; speedup 1.0000x reference)
//
#include <hip/hip_runtime.h>
#include <hip/hip_bf16.h>
#include <cstdint>

typedef __attribute__((ext_vector_type(8))) short s16x8;   // 8 bf16 = 4 VGPRs
typedef __attribute__((ext_vector_type(4))) float f32x4;   // MFMA C/D

union CV2 { __hip_bfloat162 h; uint32_t u; };

// ---------------------------------------------------------------------------
// Prep kernel: fold ln_w into W, ln_b + b into b', column sums S, and swizzle
// W' into MFMA B-fragment order as bf16.
//   Wb flat bf16 idx for (o,k): kk=k>>5, q=(k&31)>>3, j=k&7, t=o>>4, n=o&15,
//   lane l=q*16+n  ->  ((kk*4+t)*64 + l)*8 + j
// ---------------------------------------------------------------------------
__global__ void prep_kernel(const float* __restrict__ W,
                            const float* __restrict__ lnw,
                            const float* __restrict__ lnb,
                            const float* __restrict__ bias,
                            __hip_bfloat16* __restrict__ Wb,
                            float* __restrict__ Ssum,
                            float* __restrict__ bp) {
    const int o = blockIdx.x;      // 0..63
    const int tid = threadIdx.x;   // 0..255
    float s = 0.f, bb = 0.f;
    for (int k = tid; k < 768; k += 256) {
        float wraw = W[o * 768 + k];
        float wv = lnw[k] * wraw;
        s += wv;
        bb += lnb[k] * wraw;
        int kk = k >> 5, rem = k & 31;
        int q = rem >> 3, j = rem & 7;
        int t = o >> 4, n = o & 15;
        int l = q * 16 + n;
        Wb[(kk * 4 + t) * 512 + l * 8 + j] = __float2bfloat16(wv);
    }
    __shared__ float rs[4], rb[4];
    for (int off = 32; off > 0; off >>= 1) {
        s  += __shfl_down(s, off);
        bb += __shfl_down(bb, off);
    }
    int wid = tid >> 6;
    if ((tid & 63) == 0) { rs[wid] = s; rb[wid] = bb; }
    __syncthreads();
    if (tid == 0) {
        Ssum[o] = rs[0] + rs[1] + rs[2] + rs[3];
        bp[o]   = bias[o] + rb[0] + rb[1] + rb[2] + rb[3];
    }
}

// ---------------------------------------------------------------------------
// Fused LN + GEMM(768->64) + SiLU + unpatchify.
// Block = 256 thr (4 waves) handles TWO batch rows b (128 x-rows).
// Wave: 32 x-rows (2 A-frags) x 64 outs, 8 MFMAs per K-step.
// Explicit 1-step software pipeline: next step's 8 loads issued before
// current step's compute consumes the buffered ones.
// ---------------------------------------------------------------------------
__global__ __launch_bounds__(256, 4) void fused_kernel(
        const float* __restrict__ x,
        const uint4* __restrict__ Wb4,
        const float* __restrict__ Ssum,
        const float* __restrict__ bp,
        float* __restrict__ out) {
    const int bpair = blockIdx.x;          // pair of batch rows
    const int tid = threadIdx.x;
    const int w   = tid >> 6;   // wave 0..3
    const int l   = tid & 63;
    const int q   = l >> 4;     // quad 0..3
    const int n   = l & 15;

    // wave w covers x-rows [w*32, w*32+32): group g rows = w*32 + g*16 + n
    const float* xr0 = x + (size_t)(bpair * 128 + w * 32 + n) * 768 + q * 8;
    const float* xr1 = xr0 + 16 * 768;

    f32x4 acc00 = {0.f,0.f,0.f,0.f};
    f32x4 acc01 = acc00, acc02 = acc00, acc03 = acc00;
    f32x4 acc10 = acc00, acc11 = acc00, acc12 = acc00, acc13 = acc00;
    float sum0 = 0.f, ssq0 = 0.f, sum1 = 0.f, ssq1 = 0.f;

    const uint4* wbase = Wb4 + l;

    // prologue: step-0 loads
    float4 cx0a = *(const float4*)(xr0);
    float4 cx0b = *(const float4*)(xr0 + 4);
    float4 cx1a = *(const float4*)(xr1);
    float4 cx1b = *(const float4*)(xr1 + 4);
    uint4 cw0 = wbase[0], cw1 = wbase[64], cw2 = wbase[128], cw3 = wbase[192];

    #pragma unroll
    for (int kk = 0; kk < 24; kk++) {
        float4 nx0a = cx0a, nx0b = cx0b, nx1a = cx1a, nx1b = cx1b;
        uint4 nw0 = cw0, nw1 = cw1, nw2 = cw2, nw3 = cw3;
        if (kk < 23) {
            const float* p0 = xr0 + (kk + 1) * 32;
            const float* p1 = xr1 + (kk + 1) * 32;
            nx0a = *(const float4*)p0; nx0b = *(const float4*)(p0 + 4);
            nx1a = *(const float4*)p1; nx1b = *(const float4*)(p1 + 4);
            const uint4* wp = wbase + (kk + 1) * 256;
            nw0 = wp[0]; nw1 = wp[64]; nw2 = wp[128]; nw3 = wp[192];
        }

        // ---- stats (fp32, exact-ish) ----
        sum0 += ((cx0a.x + cx0a.y) + (cx0a.z + cx0a.w))
              + ((cx0b.x + cx0b.y) + (cx0b.z + cx0b.w));
        ssq0 = fmaf(cx0a.x, cx0a.x, ssq0); ssq0 = fmaf(cx0a.y, cx0a.y, ssq0);
        ssq0 = fmaf(cx0a.z, cx0a.z, ssq0); ssq0 = fmaf(cx0a.w, cx0a.w, ssq0);
        ssq0 = fmaf(cx0b.x, cx0b.x, ssq0); ssq0 = fmaf(cx0b.y, cx0b.y, ssq0);
        ssq0 = fmaf(cx0b.z, cx0b.z, ssq0); ssq0 = fmaf(cx0b.w, cx0b.w, ssq0);
        sum1 += ((cx1a.x + cx1a.y) + (cx1a.z + cx1a.w))
              + ((cx1b.x + cx1b.y) + (cx1b.z + cx1b.w));
        ssq1 = fmaf(cx1a.x, cx1a.x, ssq1); ssq1 = fmaf(cx1a.y, cx1a.y, ssq1);
        ssq1 = fmaf(cx1a.z, cx1a.z, ssq1); ssq1 = fmaf(cx1a.w, cx1a.w, ssq1);
        ssq1 = fmaf(cx1b.x, cx1b.x, ssq1); ssq1 = fmaf(cx1b.y, cx1b.y, ssq1);
        ssq1 = fmaf(cx1b.z, cx1b.z, ssq1); ssq1 = fmaf(cx1b.w, cx1b.w, ssq1);

        // ---- bf16 A-fragments ----
        CV2 c0, c1, c2, c3;
        c0.h = __float22bfloat162_rn(make_float2(cx0a.x, cx0a.y));
        c1.h = __float22bfloat162_rn(make_float2(cx0a.z, cx0a.w));
        c2.h = __float22bfloat162_rn(make_float2(cx0b.x, cx0b.y));
        c3.h = __float22bfloat162_rn(make_float2(cx0b.z, cx0b.w));
        s16x8 a0 = __builtin_bit_cast(s16x8, make_uint4(c0.u, c1.u, c2.u, c3.u));
        c0.h = __float22bfloat162_rn(make_float2(cx1a.x, cx1a.y));
        c1.h = __float22bfloat162_rn(make_float2(cx1a.z, cx1a.w));
        c2.h = __float22bfloat162_rn(make_float2(cx1b.x, cx1b.y));
        c3.h = __float22bfloat162_rn(make_float2(cx1b.z, cx1b.w));
        s16x8 a1 = __builtin_bit_cast(s16x8, make_uint4(c0.u, c1.u, c2.u, c3.u));

        s16x8 b0 = __builtin_bit_cast(s16x8, cw0);
        s16x8 b1 = __builtin_bit_cast(s16x8, cw1);
        s16x8 b2 = __builtin_bit_cast(s16x8, cw2);
        s16x8 b3 = __builtin_bit_cast(s16x8, cw3);

        acc00 = __builtin_amdgcn_mfma_f32_16x16x32_bf16(a0, b0, acc00, 0, 0, 0);
        acc01 = __builtin_amdgcn_mfma_f32_16x16x32_bf16(a0, b1, acc01, 0, 0, 0);
        acc02 = __builtin_amdgcn_mfma_f32_16x16x32_bf16(a0, b2, acc02, 0, 0, 0);
        acc03 = __builtin_amdgcn_mfma_f32_16x16x32_bf16(a0, b3, acc03, 0, 0, 0);
        acc10 = __builtin_amdgcn_mfma_f32_16x16x32_bf16(a1, b0, acc10, 0, 0, 0);
        acc11 = __builtin_amdgcn_mfma_f32_16x16x32_bf16(a1, b1, acc11, 0, 0, 0);
        acc12 = __builtin_amdgcn_mfma_f32_16x16x32_bf16(a1, b2, acc12, 0, 0, 0);
        acc13 = __builtin_amdgcn_mfma_f32_16x16x32_bf16(a1, b3, acc13, 0, 0, 0);

        cx0a = nx0a; cx0b = nx0b; cx1a = nx1a; cx1b = nx1b;
        cw0 = nw0; cw1 = nw1; cw2 = nw2; cw3 = nw3;
    }

    // ---- row stats: reduce across the 4 lanes sharing m (xor 16, 32) ----
    sum0 += __shfl_xor(sum0, 16); sum0 += __shfl_xor(sum0, 32);
    ssq0 += __shfl_xor(ssq0, 16); ssq0 += __shfl_xor(ssq0, 32);
    sum1 += __shfl_xor(sum1, 16); sum1 += __shfl_xor(sum1, 32);
    ssq1 += __shfl_xor(ssq1, 16); ssq1 += __shfl_xor(ssq1, 32);
    const float mu0   = sum0 * (1.0f / 768.0f);
    const float rstd0 = rsqrtf(ssq0 * (1.0f / 768.0f) - mu0 * mu0 + 1e-5f);
    const float mu1   = sum1 * (1.0f / 768.0f);
    const float rstd1 = rsqrtf(ssq1 * (1.0f / 768.0f) - mu1 * mu1 + 1e-5f);

    float St[4], Bt[4];
    #pragma unroll
    for (int t = 0; t < 4; t++) {
        St[t] = Ssum[t * 16 + n];   // o = 16t + n
        Bt[t] = bp[t * 16 + n];
    }

    // ---- epilogue: SiLU + unpatchify via LDS stage, coalesced stores ----
    __shared__ float sout[2][4096];
    const int bw = w >> 1;      // which b of the pair this wave feeds
    const int h  = w & 1;       // row-half within that b
    const int o2 = (n >> 2) & 3;
    const int o3 = n & 3;

    #pragma unroll
    for (int g = 0; g < 2; g++) {
        float mug   = g ? mu1   : mu0;
        float rstdg = g ? rstd1 : rstd0;
        f32x4 va[4];
        if (g == 0) { va[0] = acc00; va[1] = acc01; va[2] = acc02; va[3] = acc03; }
        else        { va[0] = acc10; va[1] = acc11; va[2] = acc12; va[3] = acc13; }
        #pragma unroll
        for (int r = 0; r < 4; r++) {
            // D layout: lane holds row m = q*4+r, col n; stats live on lane m.
            float mu_r   = __shfl(mug,   q * 4 + r);
            float rstd_r = __shfl(rstdg, q * 4 + r);
            int cc  = h * 32 + g * 16 + q * 4 + r;   // row index within this b
            int c1i = cc >> 3, c2i = cc & 7;
            int base = (c1i * 4 + o2) * 32 + c2i * 4 + o3;
            #pragma unroll
            for (int t = 0; t < 4; t++) {
                float y = rstd_r * (va[t][r] - mu_r * St[t]) + Bt[t];
                y = y / (1.0f + __expf(-y));             // SiLU
                sout[bw][t * 1024 + base] = y;           // [c][c1*4+o2][c2*4+o3]
            }
        }
    }
    __syncthreads();

    float* outp = out + (size_t)bpair * 8192;
    #pragma unroll
    for (int bb = 0; bb < 2; bb++) {
        #pragma unroll
        for (int j = 0; j < 4; j++) {
            *(float4*)(outp + bb * 4096 + j * 1024 + tid * 4) =
                *(const float4*)(&sout[bb][j * 1024 + tid * 4]);
        }
    }
}

extern "C" void kernel_launch(void* const* d_in, const int* in_sizes, int n_in,
                              void* d_out, int out_size, void* d_ws, size_t ws_size,
                              hipStream_t stream) {
    const float* x    = (const float*)d_in[0];
    const float* lnw  = (const float*)d_in[1];
    const float* lnb  = (const float*)d_in[2];
    const float* W    = (const float*)d_in[3];
    const float* bias = (const float*)d_in[4];
    float* out = (float*)d_out;

    const int B = in_sizes[0] / (64 * 768);   // 2048

    __hip_bfloat16* Wb = (__hip_bfloat16*)d_ws;                 // 98304 B
    float* Ssum = (float*)((char*)d_ws + 98304);                // 256 B
    float* bp   = (float*)((char*)d_ws + 98304 + 256);          // 256 B

    prep_kernel<<<64, 256, 0, stream>>>(W, lnw, lnb, bias, Wb, Ssum, bp);
    fused_kernel<<<B / 2, 256, 0, stream>>>(x, (const uint4*)d_ws, Ssum, bp, out);
}

// Round 3
// 635.024 us; speedup vs baseline: 1.1544x; 1.1544x over previous
//
#include <hip/hip_runtime.h>
#include <hip/hip_bf16.h>
#include <cstdint>

typedef __attribute__((ext_vector_type(8))) short s16x8;   // 8 bf16 = 4 VGPRs
typedef __attribute__((ext_vector_type(4))) float f32x4;   // MFMA C/D

union CV2 { __hip_bfloat162 h; uint32_t u; };

// ---------------------------------------------------------------------------
// Prep kernel: fold ln_w into W, ln_b + b into b', column sums S, and swizzle
// W' into MFMA B-fragment order as bf16.
//   Wb flat bf16 idx for (o,k): kk=k>>5, q=(k&31)>>3, j=k&7, t=o>>4, n=o&15,
//   lane l=q*16+n  ->  ((kk*4+t)*64 + l)*8 + j
// ---------------------------------------------------------------------------
__global__ void prep_kernel(const float* __restrict__ W,
                            const float* __restrict__ lnw,
                            const float* __restrict__ lnb,
                            const float* __restrict__ bias,
                            __hip_bfloat16* __restrict__ Wb,
                            float* __restrict__ Ssum,
                            float* __restrict__ bp) {
    const int o = blockIdx.x;      // 0..63
    const int tid = threadIdx.x;   // 0..255
    float s = 0.f, bb = 0.f;
    for (int k = tid; k < 768; k += 256) {
        float wraw = W[o * 768 + k];
        float wv = lnw[k] * wraw;
        s += wv;
        bb += lnb[k] * wraw;
        int kk = k >> 5, rem = k & 31;
        int q = rem >> 3, j = rem & 7;
        int t = o >> 4, n = o & 15;
        int l = q * 16 + n;
        Wb[(kk * 4 + t) * 512 + l * 8 + j] = __float2bfloat16(wv);
    }
    __shared__ float rs[4], rb[4];
    for (int off = 32; off > 0; off >>= 1) {
        s  += __shfl_down(s, off);
        bb += __shfl_down(bb, off);
    }
    int wid = tid >> 6;
    if ((tid & 63) == 0) { rs[wid] = s; rb[wid] = bb; }
    __syncthreads();
    if (tid == 0) {
        Ssum[o] = rs[0] + rs[1] + rs[2] + rs[3];
        bp[o]   = bias[o] + rb[0] + rb[1] + rb[2] + rb[3];
    }
}

// ---------------------------------------------------------------------------
// Fused LN + GEMM(768->64) + SiLU + unpatchify.
// Block = 256 thr (4 waves) handles TWO batch rows b (128 x-rows).
// Wave: 32 x-rows (2 A-frags) x 64 outs, 8 MFMAs per K-step.
// Explicit 1-step software pipeline.
// __launch_bounds__(256, 2): 256 unified VGPR+AGPR per wave. (256,4) clamped
// the unified file to 128 -> pipeline buffers spilled to scratch (+490 MB of
// HBM spill traffic measured in R2). Demand ~170 regs; 2-3 blocks/CU is
// plenty of TLP (Little's law needs ~22 KB in flight/CU, we have ~96 KB).
// ---------------------------------------------------------------------------
__global__ __launch_bounds__(256, 2) void fused_kernel(
        const float* __restrict__ x,
        const uint4* __restrict__ Wb4,
        const float* __restrict__ Ssum,
        const float* __restrict__ bp,
        float* __restrict__ out) {
    const int bpair = blockIdx.x;          // pair of batch rows
    const int tid = threadIdx.x;
    const int w   = tid >> 6;   // wave 0..3
    const int l   = tid & 63;
    const int q   = l >> 4;     // quad 0..3
    const int n   = l & 15;

    // wave w covers x-rows [w*32, w*32+32): group g rows = w*32 + g*16 + n
    const float* xr0 = x + (size_t)(bpair * 128 + w * 32 + n) * 768 + q * 8;
    const float* xr1 = xr0 + 16 * 768;

    f32x4 acc00 = {0.f,0.f,0.f,0.f};
    f32x4 acc01 = acc00, acc02 = acc00, acc03 = acc00;
    f32x4 acc10 = acc00, acc11 = acc00, acc12 = acc00, acc13 = acc00;
    float sum0 = 0.f, ssq0 = 0.f, sum1 = 0.f, ssq1 = 0.f;

    const uint4* wbase = Wb4 + l;

    // prologue: step-0 loads
    float4 cx0a = *(const float4*)(xr0);
    float4 cx0b = *(const float4*)(xr0 + 4);
    float4 cx1a = *(const float4*)(xr1);
    float4 cx1b = *(const float4*)(xr1 + 4);
    uint4 cw0 = wbase[0], cw1 = wbase[64], cw2 = wbase[128], cw3 = wbase[192];

    #pragma unroll
    for (int kk = 0; kk < 24; kk++) {
        float4 nx0a = cx0a, nx0b = cx0b, nx1a = cx1a, nx1b = cx1b;
        uint4 nw0 = cw0, nw1 = cw1, nw2 = cw2, nw3 = cw3;
        if (kk < 23) {
            const float* p0 = xr0 + (kk + 1) * 32;
            const float* p1 = xr1 + (kk + 1) * 32;
            nx0a = *(const float4*)p0; nx0b = *(const float4*)(p0 + 4);
            nx1a = *(const float4*)p1; nx1b = *(const float4*)(p1 + 4);
            const uint4* wp = wbase + (kk + 1) * 256;
            nw0 = wp[0]; nw1 = wp[64]; nw2 = wp[128]; nw3 = wp[192];
        }

        // ---- stats (fp32) ----
        sum0 += ((cx0a.x + cx0a.y) + (cx0a.z + cx0a.w))
              + ((cx0b.x + cx0b.y) + (cx0b.z + cx0b.w));
        ssq0 = fmaf(cx0a.x, cx0a.x, ssq0); ssq0 = fmaf(cx0a.y, cx0a.y, ssq0);
        ssq0 = fmaf(cx0a.z, cx0a.z, ssq0); ssq0 = fmaf(cx0a.w, cx0a.w, ssq0);
        ssq0 = fmaf(cx0b.x, cx0b.x, ssq0); ssq0 = fmaf(cx0b.y, cx0b.y, ssq0);
        ssq0 = fmaf(cx0b.z, cx0b.z, ssq0); ssq0 = fmaf(cx0b.w, cx0b.w, ssq0);
        sum1 += ((cx1a.x + cx1a.y) + (cx1a.z + cx1a.w))
              + ((cx1b.x + cx1b.y) + (cx1b.z + cx1b.w));
        ssq1 = fmaf(cx1a.x, cx1a.x, ssq1); ssq1 = fmaf(cx1a.y, cx1a.y, ssq1);
        ssq1 = fmaf(cx1a.z, cx1a.z, ssq1); ssq1 = fmaf(cx1a.w, cx1a.w, ssq1);
        ssq1 = fmaf(cx1b.x, cx1b.x, ssq1); ssq1 = fmaf(cx1b.y, cx1b.y, ssq1);
        ssq1 = fmaf(cx1b.z, cx1b.z, ssq1); ssq1 = fmaf(cx1b.w, cx1b.w, ssq1);

        // ---- bf16 A-fragments ----
        CV2 c0, c1, c2, c3;
        c0.h = __float22bfloat162_rn(make_float2(cx0a.x, cx0a.y));
        c1.h = __float22bfloat162_rn(make_float2(cx0a.z, cx0a.w));
        c2.h = __float22bfloat162_rn(make_float2(cx0b.x, cx0b.y));
        c3.h = __float22bfloat162_rn(make_float2(cx0b.z, cx0b.w));
        s16x8 a0 = __builtin_bit_cast(s16x8, make_uint4(c0.u, c1.u, c2.u, c3.u));
        c0.h = __float22bfloat162_rn(make_float2(cx1a.x, cx1a.y));
        c1.h = __float22bfloat162_rn(make_float2(cx1a.z, cx1a.w));
        c2.h = __float22bfloat162_rn(make_float2(cx1b.x, cx1b.y));
        c3.h = __float22bfloat162_rn(make_float2(cx1b.z, cx1b.w));
        s16x8 a1 = __builtin_bit_cast(s16x8, make_uint4(c0.u, c1.u, c2.u, c3.u));

        s16x8 b0 = __builtin_bit_cast(s16x8, cw0);
        s16x8 b1 = __builtin_bit_cast(s16x8, cw1);
        s16x8 b2 = __builtin_bit_cast(s16x8, cw2);
        s16x8 b3 = __builtin_bit_cast(s16x8, cw3);

        acc00 = __builtin_amdgcn_mfma_f32_16x16x32_bf16(a0, b0, acc00, 0, 0, 0);
        acc01 = __builtin_amdgcn_mfma_f32_16x16x32_bf16(a0, b1, acc01, 0, 0, 0);
        acc02 = __builtin_amdgcn_mfma_f32_16x16x32_bf16(a0, b2, acc02, 0, 0, 0);
        acc03 = __builtin_amdgcn_mfma_f32_16x16x32_bf16(a0, b3, acc03, 0, 0, 0);
        acc10 = __builtin_amdgcn_mfma_f32_16x16x32_bf16(a1, b0, acc10, 0, 0, 0);
        acc11 = __builtin_amdgcn_mfma_f32_16x16x32_bf16(a1, b1, acc11, 0, 0, 0);
        acc12 = __builtin_amdgcn_mfma_f32_16x16x32_bf16(a1, b2, acc12, 0, 0, 0);
        acc13 = __builtin_amdgcn_mfma_f32_16x16x32_bf16(a1, b3, acc13, 0, 0, 0);

        cx0a = nx0a; cx0b = nx0b; cx1a = nx1a; cx1b = nx1b;
        cw0 = nw0; cw1 = nw1; cw2 = nw2; cw3 = nw3;
    }

    // ---- row stats: reduce across the 4 lanes sharing m (xor 16, 32) ----
    sum0 += __shfl_xor(sum0, 16); sum0 += __shfl_xor(sum0, 32);
    ssq0 += __shfl_xor(ssq0, 16); ssq0 += __shfl_xor(ssq0, 32);
    sum1 += __shfl_xor(sum1, 16); sum1 += __shfl_xor(sum1, 32);
    ssq1 += __shfl_xor(ssq1, 16); ssq1 += __shfl_xor(ssq1, 32);
    const float mu0   = sum0 * (1.0f / 768.0f);
    const float rstd0 = rsqrtf(ssq0 * (1.0f / 768.0f) - mu0 * mu0 + 1e-5f);
    const float mu1   = sum1 * (1.0f / 768.0f);
    const float rstd1 = rsqrtf(ssq1 * (1.0f / 768.0f) - mu1 * mu1 + 1e-5f);

    float St[4], Bt[4];
    #pragma unroll
    for (int t = 0; t < 4; t++) {
        St[t] = Ssum[t * 16 + n];   // o = 16t + n
        Bt[t] = bp[t * 16 + n];
    }

    // ---- epilogue: SiLU + unpatchify via LDS stage, coalesced stores ----
    __shared__ float sout[2][4096];
    const int bw = w >> 1;      // which b of the pair this wave feeds
    const int h  = w & 1;       // row-half within that b
    const int o2 = (n >> 2) & 3;
    const int o3 = n & 3;

    #pragma unroll
    for (int g = 0; g < 2; g++) {
        float mug   = g ? mu1   : mu0;
        float rstdg = g ? rstd1 : rstd0;
        f32x4 va[4];
        if (g == 0) { va[0] = acc00; va[1] = acc01; va[2] = acc02; va[3] = acc03; }
        else        { va[0] = acc10; va[1] = acc11; va[2] = acc12; va[3] = acc13; }
        #pragma unroll
        for (int r = 0; r < 4; r++) {
            // D layout: lane holds row m = q*4+r, col n; stats live on lane m.
            float mu_r   = __shfl(mug,   q * 4 + r);
            float rstd_r = __shfl(rstdg, q * 4 + r);
            int cc  = h * 32 + g * 16 + q * 4 + r;   // row index within this b
            int c1i = cc >> 3, c2i = cc & 7;
            int base = (c1i * 4 + o2) * 32 + c2i * 4 + o3;
            #pragma unroll
            for (int t = 0; t < 4; t++) {
                float y = rstd_r * (va[t][r] - mu_r * St[t]) + Bt[t];
                y = y / (1.0f + __expf(-y));             // SiLU
                sout[bw][t * 1024 + base] = y;           // [c][c1*4+o2][c2*4+o3]
            }
        }
    }
    __syncthreads();

    float* outp = out + (size_t)bpair * 8192;
    #pragma unroll
    for (int bb = 0; bb < 2; bb++) {
        #pragma unroll
        for (int j = 0; j < 4; j++) {
            *(float4*)(outp + bb * 4096 + j * 1024 + tid * 4) =
                *(const float4*)(&sout[bb][j * 1024 + tid * 4]);
        }
    }
}

extern "C" void kernel_launch(void* const* d_in, const int* in_sizes, int n_in,
                              void* d_out, int out_size, void* d_ws, size_t ws_size,
                              hipStream_t stream) {
    const float* x    = (const float*)d_in[0];
    const float* lnw  = (const float*)d_in[1];
    const float* lnb  = (const float*)d_in[2];
    const float* W    = (const float*)d_in[3];
    const float* bias = (const float*)d_in[4];
    float* out = (float*)d_out;

    const int B = in_sizes[0] / (64 * 768);   // 2048

    __hip_bfloat16* Wb = (__hip_bfloat16*)d_ws;                 // 98304 B
    float* Ssum = (float*)((char*)d_ws + 98304);                // 256 B
    float* bp   = (float*)((char*)d_ws + 98304 + 256);          // 256 B

    prep_kernel<<<64, 256, 0, stream>>>(W, lnw, lnb, bias, Wb, Ssum, bp);
    fused_kernel<<<B / 2, 256, 0, stream>>>(x, (const uint4*)d_ws, Ssum, bp, out);
}

// Round 4
// 559.723 us; speedup vs baseline: 1.3097x; 1.1345x over previous
//
#include <hip/hip_runtime.h>
#include <hip/hip_bf16.h>
#include <cstdint>

typedef __attribute__((ext_vector_type(8))) short s16x8;   // 8 bf16 = 4 VGPRs
typedef __attribute__((ext_vector_type(4))) float f32x4;   // MFMA C/D

union CV2 { __hip_bfloat162 h; uint32_t u; };

// ---------------------------------------------------------------------------
// Prep kernel: fold ln_w into W, ln_b + b into b', column sums S, and swizzle
// W' into MFMA B-fragment order as bf16.
//   Wb flat bf16 idx for (o,k): kk=k>>5, q=(k&31)>>3, j=k&7, t=o>>4, n=o&15,
//   lane l=q*16+n  ->  ((kk*4+t)*64 + l)*8 + j
// ---------------------------------------------------------------------------
__global__ void prep_kernel(const float* __restrict__ W,
                            const float* __restrict__ lnw,
                            const float* __restrict__ lnb,
                            const float* __restrict__ bias,
                            __hip_bfloat16* __restrict__ Wb,
                            float* __restrict__ Ssum,
                            float* __restrict__ bp) {
    const int o = blockIdx.x;      // 0..63
    const int tid = threadIdx.x;   // 0..255
    float s = 0.f, bb = 0.f;
    for (int k = tid; k < 768; k += 256) {
        float wraw = W[o * 768 + k];
        float wv = lnw[k] * wraw;
        s += wv;
        bb += lnb[k] * wraw;
        int kk = k >> 5, rem = k & 31;
        int q = rem >> 3, j = rem & 7;
        int t = o >> 4, n = o & 15;
        int l = q * 16 + n;
        Wb[(kk * 4 + t) * 512 + l * 8 + j] = __float2bfloat16(wv);
    }
    __shared__ float rs[4], rb[4];
    for (int off = 32; off > 0; off >>= 1) {
        s  += __shfl_down(s, off);
        bb += __shfl_down(bb, off);
    }
    int wid = tid >> 6;
    if ((tid & 63) == 0) { rs[wid] = s; rb[wid] = bb; }
    __syncthreads();
    if (tid == 0) {
        Ssum[o] = rs[0] + rs[1] + rs[2] + rs[3];
        bp[o]   = bias[o] + rb[0] + rb[1] + rb[2] + rb[3];
    }
}

// ---------------------------------------------------------------------------
// Fused LN + GEMM(768->64) + SiLU + unpatchify, LDS-staged.
// Block = 256 thr (4 waves) = ONE batch row b (64 x-rows). Grid = 2048.
// Global x reads are fully lane-contiguous (32 lanes x one row's 512 B run),
// staged as bf16 into double-buffered LDS chunks (128 k each, row stride
// 272 B == 16 mod 128 so ds_read_b128 A-fragment reads are bank-conflict
// free). MFMA consumes raw bf16(x); LN mean/rstd folded into the epilogue
// (y = rstd*(dot - mu*S_o) + b'), stats accumulated from the fragments.
// ---------------------------------------------------------------------------
__global__ __launch_bounds__(256, 3) void fused_kernel(
        const float* __restrict__ x,
        const uint4* __restrict__ Wb4,
        const float* __restrict__ Ssum,
        const float* __restrict__ bp,
        float* __restrict__ out) {
    const int b   = blockIdx.x;
    const int tid = threadIdx.x;
    const int w   = tid >> 6;   // wave 0..3
    const int l   = tid & 63;
    const int q   = l >> 4;     // quad 0..3
    const int n   = l & 15;

    __shared__ __align__(16) char lds[2 * 17408];   // 2 x (64 rows x 272 B)

    const float* xb = x + (size_t)b * 49152;        // this b's 64x768 block
    const int srow = tid >> 5;                      // staging sub-row 0..7
    const int u    = tid & 31;                      // 32 lanes span 512 B

    // ---- stage chunk 0 (fully coalesced global reads) ----
    float4 st[8];
    #pragma unroll
    for (int j = 0; j < 8; j++)
        st[j] = *(const float4*)(xb + (j * 8 + srow) * 768 + u * 4);
    #pragma unroll
    for (int j = 0; j < 8; j++) {
        CV2 lo, hi;
        lo.h = __float22bfloat162_rn(make_float2(st[j].x, st[j].y));
        hi.h = __float22bfloat162_rn(make_float2(st[j].z, st[j].w));
        *(uint2*)(lds + (j * 8 + srow) * 272 + u * 8) = make_uint2(lo.u, hi.u);
    }
    __syncthreads();

    f32x4 acc0 = {0.f, 0.f, 0.f, 0.f};
    f32x4 acc1 = acc0, acc2 = acc0, acc3 = acc0;
    float sum = 0.f, ssq = 0.f;
    const uint4* wbl = Wb4 + l;

    #pragma unroll
    for (int c = 0; c < 6; c++) {
        // prefetch next chunk's x (global, coalesced) while computing this one
        if (c < 5) {
            #pragma unroll
            for (int j = 0; j < 8; j++)
                st[j] = *(const float4*)(xb + (j * 8 + srow) * 768
                                         + (c + 1) * 128 + u * 4);
        }

        // A-fragments for the 4 K-steps of this chunk (conflict-free b128)
        const char* bufp = lds + (c & 1) * 17408 + (w * 16 + n) * 272 + q * 16;
        uint4 fr[4];
        #pragma unroll
        for (int s = 0; s < 4; s++) fr[s] = *(const uint4*)(bufp + s * 64);

        // B-fragments: step-0 now, steps 1..3 prefetched one step ahead
        const uint4* wpc = wbl + c * 1024;
        uint4 wb0 = wpc[0], wb1 = wpc[64], wb2 = wpc[128], wb3 = wpc[192];

        #pragma unroll
        for (int s = 0; s < 4; s++) {
            uint4 nb0, nb1, nb2, nb3;
            if (s < 3) {
                const uint4* wp = wpc + (s + 1) * 256;
                nb0 = wp[0]; nb1 = wp[64]; nb2 = wp[128]; nb3 = wp[192];
            }
            // stats from the bf16 fragment (bf16->f32 is a shift)
            union { uint4 u4; unsigned short us[8]; } fu; fu.u4 = fr[s];
            #pragma unroll
            for (int j = 0; j < 8; j++) {
                float xv = __uint_as_float(((unsigned)fu.us[j]) << 16);
                sum += xv;
                ssq = fmaf(xv, xv, ssq);
            }
            s16x8 af = __builtin_bit_cast(s16x8, fr[s]);
            acc0 = __builtin_amdgcn_mfma_f32_16x16x32_bf16(
                       af, __builtin_bit_cast(s16x8, wb0), acc0, 0, 0, 0);
            acc1 = __builtin_amdgcn_mfma_f32_16x16x32_bf16(
                       af, __builtin_bit_cast(s16x8, wb1), acc1, 0, 0, 0);
            acc2 = __builtin_amdgcn_mfma_f32_16x16x32_bf16(
                       af, __builtin_bit_cast(s16x8, wb2), acc2, 0, 0, 0);
            acc3 = __builtin_amdgcn_mfma_f32_16x16x32_bf16(
                       af, __builtin_bit_cast(s16x8, wb3), acc3, 0, 0, 0);
            if (s < 3) { wb0 = nb0; wb1 = nb1; wb2 = nb2; wb3 = nb3; }
        }

        // write the prefetched chunk into the other buffer
        if (c < 5) {
            char* obuf = lds + ((c + 1) & 1) * 17408;
            #pragma unroll
            for (int j = 0; j < 8; j++) {
                CV2 lo, hi;
                lo.h = __float22bfloat162_rn(make_float2(st[j].x, st[j].y));
                hi.h = __float22bfloat162_rn(make_float2(st[j].z, st[j].w));
                *(uint2*)(obuf + (j * 8 + srow) * 272 + u * 8) =
                    make_uint2(lo.u, hi.u);
            }
        }
        __syncthreads();
    }

    // ---- row stats: reduce across the 4 lanes sharing m (xor 16, 32) ----
    sum += __shfl_xor(sum, 16); sum += __shfl_xor(sum, 32);
    ssq += __shfl_xor(ssq, 16); ssq += __shfl_xor(ssq, 32);
    const float mu   = sum * (1.0f / 768.0f);
    const float rstd = rsqrtf(ssq * (1.0f / 768.0f) - mu * mu + 1e-5f);

    float St[4], Bt[4];
    #pragma unroll
    for (int t = 0; t < 4; t++) {
        St[t] = Ssum[t * 16 + n];   // o = 16t + n
        Bt[t] = bp[t * 16 + n];
    }

    // ---- epilogue: SiLU + unpatchify via LDS stage, coalesced stores ----
    float* sout = (float*)lds;     // 16 KB, aliases x buffers (post-barrier)
    const int o2 = (n >> 2) & 3;
    const int o3 = n & 3;
    f32x4 va[4] = {acc0, acc1, acc2, acc3};
    #pragma unroll
    for (int r = 0; r < 4; r++) {
        // D layout: lane holds row m = q*4+r, col n; stats live on lane m.
        float mu_r   = __shfl(mu,   q * 4 + r);
        float rstd_r = __shfl(rstd, q * 4 + r);
        int cc  = w * 16 + q * 4 + r;
        int c1i = cc >> 3, c2i = cc & 7;
        int base = (c1i * 4 + o2) * 32 + c2i * 4 + o3;
        #pragma unroll
        for (int t = 0; t < 4; t++) {
            float y = rstd_r * (va[t][r] - mu_r * St[t]) + Bt[t];
            y = y / (1.0f + __expf(-y));             // SiLU
            sout[t * 1024 + base] = y;               // [c][c1*4+o2][c2*4+o3]
        }
    }
    __syncthreads();

    float* outp = out + (size_t)b * 4096;
    #pragma unroll
    for (int j = 0; j < 4; j++) {
        *(float4*)(outp + j * 1024 + tid * 4) =
            *(const float4*)(&sout[j * 1024 + tid * 4]);
    }
}

extern "C" void kernel_launch(void* const* d_in, const int* in_sizes, int n_in,
                              void* d_out, int out_size, void* d_ws, size_t ws_size,
                              hipStream_t stream) {
    const float* x    = (const float*)d_in[0];
    const float* lnw  = (const float*)d_in[1];
    const float* lnb  = (const float*)d_in[2];
    const float* W    = (const float*)d_in[3];
    const float* bias = (const float*)d_in[4];
    float* out = (float*)d_out;

    const int B = in_sizes[0] / (64 * 768);   // 2048

    __hip_bfloat16* Wb = (__hip_bfloat16*)d_ws;                 // 98304 B
    float* Ssum = (float*)((char*)d_ws + 98304);                // 256 B
    float* bp   = (float*)((char*)d_ws + 98304 + 256);          // 256 B

    prep_kernel<<<64, 256, 0, stream>>>(W, lnw, lnb, bias, Wb, Ssum, bp);
    fused_kernel<<<B, 256, 0, stream>>>(x, (const uint4*)d_ws, Ssum, bp, out);
}

// Round 5
// 547.627 us; speedup vs baseline: 1.3386x; 1.0221x over previous
//
#include <hip/hip_runtime.h>
#include <hip/hip_bf16.h>
#include <cstdint>

typedef __attribute__((ext_vector_type(8))) short s16x8;   // 8 bf16 = 4 VGPRs
typedef __attribute__((ext_vector_type(4))) float f32x4;   // MFMA C/D

union CV2 { __hip_bfloat162 h; uint32_t u; };

// ---------------------------------------------------------------------------
// Prep kernel: fold ln_w into W, ln_b + b into b', column sums S, and swizzle
// W' into MFMA B-fragment order as bf16.
//   Wb flat bf16 idx for (o,k): kk=k>>5, q=(k&31)>>3, j=k&7, t=o>>4, n=o&15,
//   lane l=q*16+n  ->  ((kk*4+t)*64 + l)*8 + j
// ---------------------------------------------------------------------------
__global__ void prep_kernel(const float* __restrict__ W,
                            const float* __restrict__ lnw,
                            const float* __restrict__ lnb,
                            const float* __restrict__ bias,
                            __hip_bfloat16* __restrict__ Wb,
                            float* __restrict__ Ssum,
                            float* __restrict__ bp) {
    const int o = blockIdx.x;      // 0..63
    const int tid = threadIdx.x;   // 0..255
    float s = 0.f, bb = 0.f;
    for (int k = tid; k < 768; k += 256) {
        float wraw = W[o * 768 + k];
        float wv = lnw[k] * wraw;
        s += wv;
        bb += lnb[k] * wraw;
        int kk = k >> 5, rem = k & 31;
        int q = rem >> 3, j = rem & 7;
        int t = o >> 4, n = o & 15;
        int l = q * 16 + n;
        Wb[(kk * 4 + t) * 512 + l * 8 + j] = __float2bfloat16(wv);
    }
    __shared__ float rs[4], rb[4];
    for (int off = 32; off > 0; off >>= 1) {
        s  += __shfl_down(s, off);
        bb += __shfl_down(bb, off);
    }
    int wid = tid >> 6;
    if ((tid & 63) == 0) { rs[wid] = s; rb[wid] = bb; }
    __syncthreads();
    if (tid == 0) {
        Ssum[o] = rs[0] + rs[1] + rs[2] + rs[3];
        bp[o]   = bias[o] + rb[0] + rb[1] + rb[2] + rb[3];
    }
}

// ---------------------------------------------------------------------------
// Fused LN + GEMM(768->64) + SiLU + unpatchify, fully LDS-decoupled pipeline.
// KEY (R4 post-mortem): gfx950 vector-mem loads complete IN ORDER on one
// vmcnt queue -> an L1-fast Wb load issued after an HBM x load inherits the
// HBM latency at its consumption point. Fix: inner loop reads BOTH operands
// from LDS (lgkm queue only); the vm queue holds nothing but next-chunk
// staging loads (x 8 KB + Wb 1 KB per wave), issued at the end of chunk c
// and drained at the end of chunk c+1 -> sustained ~96 KB in flight per CU.
// Block = 256 thr (4 waves) = one batch row b (64 x-rows). Grid = 2048.
// x staged as bf16, row stride 272 B (conflict-free ds_read_b128 A-frags).
// Wb chunk staged as identity copy, 16 KB (conflict-free B-frag reads).
// LDS 67.6 KB -> 2 blocks/CU.
// ---------------------------------------------------------------------------
__global__ __launch_bounds__(256, 2) void fused_kernel(
        const float* __restrict__ x,
        const uint4* __restrict__ Wb4,
        const float* __restrict__ Ssum,
        const float* __restrict__ bp,
        float* __restrict__ out) {
    const int b   = blockIdx.x;
    const int tid = threadIdx.x;
    const int w   = tid >> 6;   // wave 0..3
    const int l   = tid & 63;
    const int q   = l >> 4;     // quad 0..3
    const int n   = l & 15;

    // [0,34816): x double buffer; [34816,67584): Wb double buffer
    __shared__ __align__(16) char lds[2 * 17408 + 2 * 16384];

    const float* xb = x + (size_t)b * 49152;        // this b's 64x768 block
    const int srow = tid >> 5;                      // staging sub-row 0..7
    const int u    = tid & 31;                      // 32 lanes span 512 B

    float4 st[8];
    uint4  wst[4];

    // ---- stage chunk 0 ----
    #pragma unroll
    for (int j = 0; j < 8; j++)
        st[j] = *(const float4*)(xb + (j * 8 + srow) * 768 + u * 4);
    #pragma unroll
    for (int j = 0; j < 4; j++)
        wst[j] = Wb4[tid + j * 256];
    #pragma unroll
    for (int j = 0; j < 8; j++) {
        CV2 lo, hi;
        lo.h = __float22bfloat162_rn(make_float2(st[j].x, st[j].y));
        hi.h = __float22bfloat162_rn(make_float2(st[j].z, st[j].w));
        *(uint2*)(lds + (j * 8 + srow) * 272 + u * 8) = make_uint2(lo.u, hi.u);
    }
    #pragma unroll
    for (int j = 0; j < 4; j++)
        *(uint4*)(lds + 34816 + (tid + j * 256) * 16) = wst[j];

    // ---- issue chunk-1 staging loads (in flight across chunk-0 compute) ----
    #pragma unroll
    for (int j = 0; j < 8; j++)
        st[j] = *(const float4*)(xb + (j * 8 + srow) * 768 + 128 + u * 4);
    #pragma unroll
    for (int j = 0; j < 4; j++)
        wst[j] = Wb4[1024 + tid + j * 256];
    __syncthreads();

    f32x4 acc0 = {0.f, 0.f, 0.f, 0.f};
    f32x4 acc1 = acc0, acc2 = acc0, acc3 = acc0;
    float sum = 0.f, ssq = 0.f;

    #pragma unroll
    for (int c = 0; c < 6; c++) {
        // ---- compute chunk c: pure LDS + MFMA, no vm-queue dependency ----
        const char* xbp = lds + (c & 1) * 17408 + (w * 16 + n) * 272 + q * 16;
        uint4 fr[4];
        #pragma unroll
        for (int s = 0; s < 4; s++) fr[s] = *(const uint4*)(xbp + s * 64);

        const char* wbp = lds + 34816 + (c & 1) * 16384 + l * 16;

        #pragma unroll
        for (int s = 0; s < 4; s++) {
            // stats from the bf16 fragment (bf16->f32 is a shift)
            union { uint4 u4; unsigned short us[8]; } fu; fu.u4 = fr[s];
            #pragma unroll
            for (int j = 0; j < 8; j++) {
                float xv = __uint_as_float(((unsigned)fu.us[j]) << 16);
                sum += xv;
                ssq = fmaf(xv, xv, ssq);
            }
            uint4 wb0 = *(const uint4*)(wbp + (s * 4 + 0) * 1024);
            uint4 wb1 = *(const uint4*)(wbp + (s * 4 + 1) * 1024);
            uint4 wb2 = *(const uint4*)(wbp + (s * 4 + 2) * 1024);
            uint4 wb3 = *(const uint4*)(wbp + (s * 4 + 3) * 1024);
            s16x8 af = __builtin_bit_cast(s16x8, fr[s]);
            acc0 = __builtin_amdgcn_mfma_f32_16x16x32_bf16(
                       af, __builtin_bit_cast(s16x8, wb0), acc0, 0, 0, 0);
            acc1 = __builtin_amdgcn_mfma_f32_16x16x32_bf16(
                       af, __builtin_bit_cast(s16x8, wb1), acc1, 0, 0, 0);
            acc2 = __builtin_amdgcn_mfma_f32_16x16x32_bf16(
                       af, __builtin_bit_cast(s16x8, wb2), acc2, 0, 0, 0);
            acc3 = __builtin_amdgcn_mfma_f32_16x16x32_bf16(
                       af, __builtin_bit_cast(s16x8, wb3), acc3, 0, 0, 0);
        }

        // ---- staging: write chunk c+1 (drains vm queue), issue chunk c+2 ----
        if (c < 5) {
            char* xo = lds + ((c + 1) & 1) * 17408;
            char* wo = lds + 34816 + ((c + 1) & 1) * 16384;
            #pragma unroll
            for (int j = 0; j < 8; j++) {
                CV2 lo, hi;
                lo.h = __float22bfloat162_rn(make_float2(st[j].x, st[j].y));
                hi.h = __float22bfloat162_rn(make_float2(st[j].z, st[j].w));
                *(uint2*)(xo + (j * 8 + srow) * 272 + u * 8) =
                    make_uint2(lo.u, hi.u);
            }
            #pragma unroll
            for (int j = 0; j < 4; j++)
                *(uint4*)(wo + (tid + j * 256) * 16) = wst[j];
            if (c < 4) {
                #pragma unroll
                for (int j = 0; j < 8; j++)
                    st[j] = *(const float4*)(xb + (j * 8 + srow) * 768
                                             + (c + 2) * 128 + u * 4);
                #pragma unroll
                for (int j = 0; j < 4; j++)
                    wst[j] = Wb4[(c + 2) * 1024 + tid + j * 256];
            }
            __syncthreads();
        }
    }

    // ---- row stats: reduce across the 4 lanes sharing m (xor 16, 32) ----
    sum += __shfl_xor(sum, 16); sum += __shfl_xor(sum, 32);
    ssq += __shfl_xor(ssq, 16); ssq += __shfl_xor(ssq, 32);
    const float mu   = sum * (1.0f / 768.0f);
    const float rstd = rsqrtf(ssq * (1.0f / 768.0f) - mu * mu + 1e-5f);

    float St[4], Bt[4];
    #pragma unroll
    for (int t = 0; t < 4; t++) {
        St[t] = Ssum[t * 16 + n];   // o = 16t + n
        Bt[t] = bp[t * 16 + n];
    }

    // ---- epilogue: SiLU + unpatchify via LDS stage, coalesced stores ----
    // sout occupies [0,16384) = x buf0; chunk 5 read x buf1 / Wb buf1 only.
    float* sout = (float*)lds;
    const int o2 = (n >> 2) & 3;
    const int o3 = n & 3;
    f32x4 va[4] = {acc0, acc1, acc2, acc3};
    #pragma unroll
    for (int r = 0; r < 4; r++) {
        // D layout: lane holds row m = q*4+r, col n; stats live on lane m.
        float mu_r   = __shfl(mu,   q * 4 + r);
        float rstd_r = __shfl(rstd, q * 4 + r);
        int cc  = w * 16 + q * 4 + r;
        int c1i = cc >> 3, c2i = cc & 7;
        int base = (c1i * 4 + o2) * 32 + c2i * 4 + o3;
        #pragma unroll
        for (int t = 0; t < 4; t++) {
            float y = rstd_r * (va[t][r] - mu_r * St[t]) + Bt[t];
            y = y / (1.0f + __expf(-y));             // SiLU
            sout[t * 1024 + base] = y;               // [c][c1*4+o2][c2*4+o3]
        }
    }
    __syncthreads();

    float* outp = out + (size_t)b * 4096;
    #pragma unroll
    for (int j = 0; j < 4; j++) {
        *(float4*)(outp + j * 1024 + tid * 4) =
            *(const float4*)(&sout[j * 1024 + tid * 4]);
    }
}

extern "C" void kernel_launch(void* const* d_in, const int* in_sizes, int n_in,
                              void* d_out, int out_size, void* d_ws, size_t ws_size,
                              hipStream_t stream) {
    const float* x    = (const float*)d_in[0];
    const float* lnw  = (const float*)d_in[1];
    const float* lnb  = (const float*)d_in[2];
    const float* W    = (const float*)d_in[3];
    const float* bias = (const float*)d_in[4];
    float* out = (float*)d_out;

    const int B = in_sizes[0] / (64 * 768);   // 2048

    __hip_bfloat16* Wb = (__hip_bfloat16*)d_ws;                 // 98304 B
    float* Ssum = (float*)((char*)d_ws + 98304);                // 256 B
    float* bp   = (float*)((char*)d_ws + 98304 + 256);          // 256 B

    prep_kernel<<<64, 256, 0, stream>>>(W, lnw, lnb, bias, Wb, Ssum, bp);
    fused_kernel<<<B, 256, 0, stream>>>(x, (const uint4*)d_ws, Ssum, bp, out);
}